// Round 1
// baseline (321.958 us; speedup 1.0000x reference)
//
#include <hip/hip_runtime.h>

#define NPTS   64
#define NCOLS  500000
#define NANG   2016        // 64*63/2
#define NFULL  7812        // NCOLS / 64 (32-col tail handled separately)
#define BLOCKS 768         // 3 blocks/CU * 256 CUs (LDS 48KB -> 3/CU co-resident)
#define WSTRIDE (BLOCKS * 4)

typedef __attribute__((ext_vector_type(8))) short bf16x8;
typedef __attribute__((ext_vector_type(4))) float f32x4;

static __device__ __forceinline__ short f2bf(float f) {
    union { float f; unsigned u; } uf; uf.f = f;
    unsigned u = uf.u;
    unsigned r = (u + 0x7fffu + ((u >> 16) & 1u)) >> 16;  // RNE bf16
    return (short)r;
}

// rotations before round i (iTop = i): S(i) = 63i - i(i-1)/2
static __host__ __device__ constexpr int rotS(int i) { return 63 * i - i * (i - 1) / 2; }

// ---------------------------------------------------------------------------
// Chunk chain: rounds [I0, I1) of the iTop loop applied to identity columns.
// Thread = column; rows I0..63 live in REGISTERS with fully static indices.
// csn already staged in LDS (chunk-relative). Writes full 64x64 P to LDS.
// ---------------------------------------------------------------------------
template<int I0, int I1>
__device__ __forceinline__ void chunk_lds(const float2* __restrict__ csn,
                                          float* __restrict__ P, int lane) {
    float q[64 - I0];
#pragma unroll
    for (int r = I0; r < 64; ++r) q[r - I0] = (r == lane) ? 1.0f : 0.0f;

    int k = 0;
#pragma unroll
    for (int i = I0; i < I1; ++i) {
#pragma unroll
        for (int ib = i + 1; ib < 64; ++ib, ++k) {
            float c = csn[k].x, s = csn[k].y;
            float t = q[i - I0], b = q[ib - I0];
            q[ib - I0] = s * t + c * b;   // both use OLD q[i] (matches ref)
            q[i - I0]  = c * t - s * b;
        }
        P[i * 64 + lane] = q[i - I0];     // row i final -> retire register
    }
#pragma unroll
    for (int r = 0; r < I0; ++r) P[r * 64 + lane] = (r == lane) ? 1.0f : 0.0f;
#pragma unroll
    for (int r = I1; r < 64; ++r) P[r * 64 + lane] = q[r - I0];
}

// ---------------------------------------------------------------------------
// Single fused kernel:
//   phase 0: stage cos/sin of all 2016 angles into LDS           (all 256 thr)
//   phase 1: P0 = rounds 0..18 (1026 rots, wave 0)
//            P1 = rounds 19..62 (990 rots, wave 1)   -> LDS
//   phase 2: M = diag(mus) * P1 * P0 (fp32, in-LDS 64^3 matmul)  (all 256 thr)
//   phase 3: afrag <- bf16(M); persistent grid-stride MFMA streaming
// Every block computes M redundantly (~6 us, fully parallel) — this removes
// the 3 tiny-grid setup launches during which the GPU was idle.
// ---------------------------------------------------------------------------
__global__ __launch_bounds__(256) void fused_ortho(const float* __restrict__ X,
                                                   const float* __restrict__ angles,
                                                   const float* __restrict__ mus,
                                                   float* __restrict__ out) {
    __shared__ __align__(16) float sm[12288];   // 48 KB: [csn|M][P0][P1]
    const int tid  = threadIdx.x;
    const int lane = tid & 63;
    const int wave = __builtin_amdgcn_readfirstlane(tid >> 6);

    // ---- phase 0: stage cos/sin ----
    float2* csn = (float2*)sm;                  // 2016 * 8B = 16128 B < 16 KB slot
    for (int t = tid; t < NANG; t += 256) {
        float s, c;
        sincosf(angles[t], &s, &c);
        csn[t] = make_float2(c, s);
    }
    __syncthreads();

    // ---- phase 1: two parallel chunk chains ----
    float* P0 = sm + 4096;
    float* P1 = sm + 8192;
    if (wave == 0)      chunk_lds<0, 19>(csn, P0, lane);             // 1026 rots
    else if (wave == 1) chunk_lds<19, 63>(csn + rotS(19), P1, lane); // 990 rots
    __syncthreads();

    // ---- phase 2: M = diag(mus) * P1 * P0 -> sm[0..4096) (overwrites csn) ----
    {
        float acc[16] = {0.f};
#pragma unroll 4
        for (int k0 = 0; k0 < 64; k0 += 4) {
            float lo0 = P0[(k0 + 0) * 64 + lane];
            float lo1 = P0[(k0 + 1) * 64 + lane];
            float lo2 = P0[(k0 + 2) * 64 + lane];
            float lo3 = P0[(k0 + 3) * 64 + lane];
#pragma unroll
            for (int r = 0; r < 16; ++r) {
                const f32x4 h = *(const f32x4*)&P1[(wave * 16 + r) * 64 + k0]; // LDS broadcast
                acc[r] = fmaf(h[0], lo0, acc[r]);
                acc[r] = fmaf(h[1], lo1, acc[r]);
                acc[r] = fmaf(h[2], lo2, acc[r]);
                acc[r] = fmaf(h[3], lo3, acc[r]);
            }
        }
        // csn reads all finished before the post-phase-1 barrier; safe to overwrite
#pragma unroll
        for (int r = 0; r < 16; ++r)
            sm[(wave * 16 + r) * 64 + lane] = acc[r] * mus[wave * 16 + r];
    }
    __syncthreads();

    // ---- phase 3: afrag from LDS, then persistent streaming ----
    const int laneN = lane & 15;
    const int quad  = lane >> 4;

    bf16x8 afrag[4][2];
#pragma unroll
    for (int t = 0; t < 4; ++t) {
#pragma unroll
        for (int q = 0; q < 2; ++q) {
            const float* src = sm + (t * 16 + laneN) * 64 + q * 32 + quad * 8;
            bf16x8 f;
#pragma unroll
            for (int j = 0; j < 8; ++j) f[j] = f2bf(src[j]);
            afrag[t][q] = f;
        }
    }

    const int gw = blockIdx.x * 4 + wave;

    for (int s = gw; s < NFULL; s += WSTRIDE) {   // ~2.5 stripes per wave
        const long col0 = (long)s * 64 + 4 * laneN;
        const float* xb = X + col0;

        bf16x8 bfrag[4][2];
#pragma unroll
        for (int q = 0; q < 2; ++q) {
#pragma unroll
            for (int j = 0; j < 8; ++j) {
                const int kk = q * 32 + quad * 8 + j;
                f32x4 v = *(const f32x4*)(xb + (long)kk * NCOLS);
#pragma unroll
                for (int u = 0; u < 4; ++u)
                    bfrag[u][q][j] = f2bf(v[u]);
            }
        }

#pragma unroll
        for (int t = 0; t < 4; ++t) {
            f32x4 acc[4];
#pragma unroll
            for (int u = 0; u < 4; ++u) {
                f32x4 a = {0.f, 0.f, 0.f, 0.f};
                a = __builtin_amdgcn_mfma_f32_16x16x32_bf16(afrag[t][0], bfrag[u][0], a, 0, 0, 0);
                a = __builtin_amdgcn_mfma_f32_16x16x32_bf16(afrag[t][1], bfrag[u][1], a, 0, 0, 0);
                acc[u] = a;
            }
#pragma unroll
            for (int rr = 0; rr < 4; ++rr) {
                const int row = t * 16 + quad * 4 + rr;
                f32x4 o = { acc[0][rr], acc[1][rr], acc[2][rr], acc[3][rr] };
                __builtin_nontemporal_store(o, (f32x4*)(out + (long)row * NCOLS + col0));
            }
        }
    }

    if (gw < 2) {  // 32-col tail
        const int col = NFULL * 64 + gw * 16 + laneN;
        const float* xb = X + col;
        bf16x8 bfrag[2];
#pragma unroll
        for (int q = 0; q < 2; ++q) {
            bf16x8 f;
#pragma unroll
            for (int j = 0; j < 8; ++j)
                f[j] = f2bf(xb[(long)(q * 32 + quad * 8 + j) * NCOLS]);
            bfrag[q] = f;
        }
#pragma unroll
        for (int t = 0; t < 4; ++t) {
            f32x4 a = {0.f, 0.f, 0.f, 0.f};
            a = __builtin_amdgcn_mfma_f32_16x16x32_bf16(afrag[t][0], bfrag[0], a, 0, 0, 0);
            a = __builtin_amdgcn_mfma_f32_16x16x32_bf16(afrag[t][1], bfrag[1], a, 0, 0, 0);
#pragma unroll
            for (int rr = 0; rr < 4; ++rr)
                __builtin_nontemporal_store(a[rr],
                    out + (long)(t * 16 + quad * 4 + rr) * NCOLS + col);
        }
    }
}

extern "C" void kernel_launch(void* const* d_in, const int* in_sizes, int n_in,
                              void* d_out, int out_size, void* d_ws, size_t ws_size,
                              hipStream_t stream) {
    const float* X      = (const float*)d_in[0];
    const float* angles = (const float*)d_in[1];
    const float* mus    = (const float*)d_in[2];
    fused_ortho<<<BLOCKS, 256, 0, stream>>>(X, angles, mus, (float*)d_out);
}

// Round 3
// 269.394 us; speedup vs baseline: 1.1951x; 1.1951x over previous
//
#include <hip/hip_runtime.h>

#define NPTS   64
#define NCOLS  500000
#define NANG   2016        // 64*63/2
#define NFULL  7812        // NCOLS / 64 (32-col tail handled separately)
#define TPB    512         // 8 waves/block
#define BLOCKS 512         // 2 blocks/CU * 256 CUs = exact residency (one generation)
#define WSTRIDE (BLOCKS * 8)   // 4096 global waves

typedef __attribute__((ext_vector_type(8))) short bf16x8;
typedef __attribute__((ext_vector_type(4))) float f32x4;

static __device__ __forceinline__ short f2bf(float f) {
    union { float f; unsigned u; } uf; uf.f = f;
    unsigned u = uf.u;
    unsigned r = (u + 0x7fffu + ((u >> 16) & 1u)) >> 16;  // RNE bf16
    return (short)r;
}

// rotations before round i (iTop = i): S(i) = 63i - i(i-1)/2
static __host__ __device__ constexpr int rotS(int i) { return 63 * i - i * (i - 1) / 2; }

// ---------------------------------------------------------------------------
// ROLLED Givens chain on an LDS-resident 64x64 P (thread = column).
// Rotation (i,ib) touches only column `lane` of rows i,ib -> fully
// thread-private: t = P[i][lane] stays in a register across the inner loop,
// only b = P[ib][lane] round-trips LDS (stride-1 -> conflict-free).
// ~30-instruction body: no I-cache streaming, no q[64] register array.
// ---------------------------------------------------------------------------
__device__ __forceinline__ void chain_rolled(const float2* __restrict__ csn,
                                             float* __restrict__ P,
                                             int lane, int I0, int I1) {
    for (int r = 0; r < 64; ++r) P[r * 64 + lane] = (r == lane) ? 1.0f : 0.0f;
    int k = 0;
#pragma unroll 1
    for (int i = I0; i < I1; ++i) {
        float t = P[i * 64 + lane];
#pragma unroll 4
        for (int ib = i + 1; ib < 64; ++ib, ++k) {
            float2 cs = csn[k];                    // (cos, sin), LDS broadcast
            float b = P[ib * 64 + lane];
            P[ib * 64 + lane] = cs.y * t + cs.x * b;   // vb' = s*vt + c*vb (old vt)
            t = cs.x * t - cs.y * b;                   // vt' = c*vt - s*vb
        }
        P[i * 64 + lane] = t;
    }
}

// ---------------------------------------------------------------------------
// Single fused kernel (512 thr, 48KB LDS, VGPR<=128 -> 16 waves/CU):
//   phase 0: cos/sin of 2016 angles -> LDS                       (all threads)
//   phase 1: P0 = rounds 0..18 (1026 rots, wave 0)
//            P1 = rounds 19..62 (990 rots, wave 1)  [rolled chains]
//   phase 2: M = diag(mus) * P1 * P0 (fp32, in-LDS)   8 waves x 8 rows
//   phase 3: afrag <- bf16(M); grid-stride MFMA streaming (~2 stripes/wave)
// ---------------------------------------------------------------------------
__global__ __launch_bounds__(TPB, 4) void fused_ortho(const float* __restrict__ X,
                                                      const float* __restrict__ angles,
                                                      const float* __restrict__ mus,
                                                      float* __restrict__ out) {
    __shared__ __align__(16) float sm[12288];   // 48 KB: [csn|M][P0][P1]
    const int tid  = threadIdx.x;
    const int lane = tid & 63;
    const int wave = __builtin_amdgcn_readfirstlane(tid >> 6);

    // ---- phase 0: stage cos/sin ----
    float2* csn = (float2*)sm;                  // 2016 * 8B = 16128 B
    for (int t = tid; t < NANG; t += TPB) {
        float s, c;
        sincosf(angles[t], &s, &c);
        csn[t] = make_float2(c, s);
    }
    __syncthreads();

    // ---- phase 1: two parallel rolled chains ----
    float* P0 = sm + 4096;
    float* P1 = sm + 8192;
    if (wave == 0)      chain_rolled(csn, P0, lane, 0, 19);             // 1026 rots
    else if (wave == 1) chain_rolled(csn + rotS(19), P1, lane, 19, 63); // 990 rots
    __syncthreads();

    // ---- phase 2: M = diag(mus) * P1 * P0 -> sm[0..4096) (csn dead) ----
    {
        const int row0 = wave * 8;
        float acc[8] = {0.f};
#pragma unroll 4
        for (int k0 = 0; k0 < 64; k0 += 4) {
            float lo0 = P0[(k0 + 0) * 64 + lane];
            float lo1 = P0[(k0 + 1) * 64 + lane];
            float lo2 = P0[(k0 + 2) * 64 + lane];
            float lo3 = P0[(k0 + 3) * 64 + lane];
#pragma unroll
            for (int r = 0; r < 8; ++r) {
                const f32x4 h = *(const f32x4*)&P1[(row0 + r) * 64 + k0]; // broadcast
                acc[r] = fmaf(h[0], lo0, acc[r]);
                acc[r] = fmaf(h[1], lo1, acc[r]);
                acc[r] = fmaf(h[2], lo2, acc[r]);
                acc[r] = fmaf(h[3], lo3, acc[r]);
            }
        }
#pragma unroll
        for (int r = 0; r < 8; ++r)
            sm[(row0 + r) * 64 + lane] = acc[r] * mus[row0 + r];
    }
    __syncthreads();

    // ---- phase 3: afrag from LDS, then persistent streaming ----
    const int laneN = lane & 15;
    const int quad  = lane >> 4;

    bf16x8 afrag[4][2];
#pragma unroll
    for (int t = 0; t < 4; ++t) {
#pragma unroll
        for (int q = 0; q < 2; ++q) {
            const float* src = sm + (t * 16 + laneN) * 64 + q * 32 + quad * 8;
            bf16x8 f;
#pragma unroll
            for (int j = 0; j < 8; ++j) f[j] = f2bf(src[j]);
            afrag[t][q] = f;
        }
    }

    const int gw = blockIdx.x * 8 + wave;

    for (int s = gw; s < NFULL; s += WSTRIDE) {   // ~2 stripes per wave
        const long col0 = (long)s * 64 + 4 * laneN;
        const float* xb = X + col0;

        bf16x8 bfrag[4][2];
#pragma unroll
        for (int q = 0; q < 2; ++q) {
#pragma unroll
            for (int j = 0; j < 8; ++j) {
                const int kk = q * 32 + quad * 8 + j;
                f32x4 v = *(const f32x4*)(xb + (long)kk * NCOLS);
#pragma unroll
                for (int u = 0; u < 4; ++u)
                    bfrag[u][q][j] = f2bf(v[u]);
            }
        }

#pragma unroll
        for (int t = 0; t < 4; ++t) {
            f32x4 acc[4];
#pragma unroll
            for (int u = 0; u < 4; ++u) {
                f32x4 a = {0.f, 0.f, 0.f, 0.f};
                a = __builtin_amdgcn_mfma_f32_16x16x32_bf16(afrag[t][0], bfrag[u][0], a, 0, 0, 0);
                a = __builtin_amdgcn_mfma_f32_16x16x32_bf16(afrag[t][1], bfrag[u][1], a, 0, 0, 0);
                acc[u] = a;
            }
#pragma unroll
            for (int rr = 0; rr < 4; ++rr) {
                const int row = t * 16 + quad * 4 + rr;
                f32x4 o = { acc[0][rr], acc[1][rr], acc[2][rr], acc[3][rr] };
                __builtin_nontemporal_store(o, (f32x4*)(out + (long)row * NCOLS + col0));
            }
        }
    }

    if (gw < 2) {  // 32-col tail
        const int col = NFULL * 64 + gw * 16 + laneN;
        const float* xb = X + col;
        bf16x8 bfrag[2];
#pragma unroll
        for (int q = 0; q < 2; ++q) {
            bf16x8 f;
#pragma unroll
            for (int j = 0; j < 8; ++j)
                f[j] = f2bf(xb[(long)(q * 32 + quad * 8 + j) * NCOLS]);
            bfrag[q] = f;
        }
#pragma unroll
        for (int t = 0; t < 4; ++t) {
            f32x4 a = {0.f, 0.f, 0.f, 0.f};
            a = __builtin_amdgcn_mfma_f32_16x16x32_bf16(afrag[t][0], bfrag[0], a, 0, 0, 0);
            a = __builtin_amdgcn_mfma_f32_16x16x32_bf16(afrag[t][1], bfrag[1], a, 0, 0, 0);
#pragma unroll
            for (int rr = 0; rr < 4; ++rr)
                __builtin_nontemporal_store(a[rr],
                    out + (long)(t * 16 + quad * 4 + rr) * NCOLS + col);
        }
    }
}

extern "C" void kernel_launch(void* const* d_in, const int* in_sizes, int n_in,
                              void* d_out, int out_size, void* d_ws, size_t ws_size,
                              hipStream_t stream) {
    const float* X      = (const float*)d_in[0];
    const float* angles = (const float*)d_in[1];
    const float* mus    = (const float*)d_in[2];
    fused_ortho<<<BLOCKS, TPB, 0, stream>>>(X, angles, mus, (float*)d_out);
}